// Round 1
// baseline (2248.091 us; speedup 1.0000x reference)
//
#include <hip/hip_runtime.h>
#include <stdint.h>

// Problem constants (fixed by the reference)
#define Bn 32
#define Cn 64
#define Vn 1024
#define Tn 24
#define Gn 192   // 3*C
#define O4 256   // 4*C

typedef __attribute__((ext_vector_type(8))) short bh8;   // 8 x bf16 (MFMA A/B frag)
typedef __attribute__((ext_vector_type(4))) short bh4;   // 4 x bf16 packed store
typedef __attribute__((ext_vector_type(4))) float f32x4; // MFMA C/D frag

__device__ __forceinline__ float bf2f(unsigned short u){
  union { unsigned int i; float f; } x; x.i = ((unsigned int)u) << 16; return x.f;
}
__device__ __forceinline__ unsigned short f2bf(float f){
  union { float f; unsigned int i; } x; x.f = f;
  unsigned int u = x.i;
  return (unsigned short)((u + 0x7fffu + ((u >> 16) & 1u)) >> 16); // RNE
}
__device__ __forceinline__ float sigm(float x){ return 1.f/(1.f+__expf(-x)); }
__device__ __forceinline__ float tanhfast(float x){ return 1.f - 2.f/(__expf(2.f*x)+1.f); }
__device__ __forceinline__ f32x4 fzero(){ f32x4 z = {0.f,0.f,0.f,0.f}; return z; }

// MFMA 16x16x32 frag loader (TN convention: both operands row-major with k contiguous).
// lane l holds X[idx = r0 + mf*16 + (l&15)][k = k0 + (l>>4)*8 + j], j=0..7  -> one b128 load.
__device__ __forceinline__ bh8 ld_frag(const unsigned short* base, int stride, int r0, int mf,
                                       int k0, int lane){
  int r  = r0 + mf*16 + (lane & 15);
  int kk = k0 + ((lane >> 4) << 3);
  return *(const bh8*)(base + (size_t)r * stride + kk);
}

// ---------------------------------------------------------------------------
// Prep: permute W_gout rows to o' = c*4 + gate (so one lane's f32x4 acc = i,f,g,o
// of a single channel), quantize to bf16; permute bias.
__global__ void k_prep_w(const float* __restrict__ Wg, const float* __restrict__ bg,
                         unsigned short* __restrict__ Wperm, float* __restrict__ bperm){
  int op = threadIdx.x;              // 0..255 = o'
  int gate = op & 3, c = op >> 2;
  int oo = gate * 64 + c;            // original row in W_gout
  for (int g = 0; g < Gn; ++g)
    Wperm[op * Gn + g] = f2bf(Wg[(size_t)oo * Gn + g]);
  bperm[op] = bg[oo];
}

// Quantize + transpose a 1024x1024 fp32 matrix: dst (optional) = bf16(src), dstT = bf16(src^T)
__global__ void k_transq(const float* __restrict__ src, unsigned short* dst,
                         unsigned short* __restrict__ dstT){
  __shared__ float tile[64][65];
  int j0 = blockIdx.x * 64, i0 = blockIdx.y * 64;
  for (int e = threadIdx.x; e < 4096; e += 256){
    int r = e >> 6, col = e & 63;
    float v = src[(size_t)(i0 + r) * Vn + j0 + col];
    if (dst) dst[(size_t)(i0 + r) * Vn + j0 + col] = f2bf(v);
    tile[r][col] = v;
  }
  __syncthreads();
  for (int e = threadIdx.x; e < 4096; e += 256){
    int r = e >> 6, col = e & 63;
    dstT[(size_t)(j0 + r) * Vn + i0 + col] = f2bf(tile[col][r]);
  }
}

// A2 = A @ A  (bf16 MFMA, fp32 out). D[m][n] = sum_k Ab[m][k] * ATb[n][k].
__global__ __launch_bounds__(64) void k_gemm_a2(const unsigned short* __restrict__ Ab,
                                                const unsigned short* __restrict__ ATb,
                                                float* __restrict__ A2){
  int lane = threadIdx.x;
  int n0 = blockIdx.x * 64, m0 = blockIdx.y * 64;
  f32x4 acc[4][4];
  #pragma unroll
  for (int i=0;i<4;i++)
    #pragma unroll
    for (int j=0;j<4;j++) acc[i][j] = fzero();
  #pragma unroll 2
  for (int k = 0; k < Vn; k += 32){
    bh8 a[4], b[4];
    #pragma unroll
    for (int mf=0; mf<4; ++mf) a[mf] = ld_frag(Ab, Vn, m0, mf, k, lane);
    #pragma unroll
    for (int nf=0; nf<4; ++nf) b[nf] = ld_frag(ATb, Vn, n0, nf, k, lane);
    #pragma unroll
    for (int mf=0; mf<4; ++mf)
      #pragma unroll
      for (int nf=0; nf<4; ++nf)
        acc[mf][nf] = __builtin_amdgcn_mfma_f32_16x16x32_bf16(a[mf], b[nf], acc[mf][nf], 0,0,0);
  }
  #pragma unroll
  for (int mf=0; mf<4; ++mf){
    int rb = m0 + mf*16 + ((lane>>4)<<2);
    #pragma unroll
    for (int nf=0; nf<4; ++nf){
      int cc = n0 + nf*16 + (lane&15);
      #pragma unroll
      for (int r=0;r<4;r++) A2[(size_t)(rb+r)*Vn + cc] = acc[mf][nf][r];
    }
  }
}

// x (B,C,V,T) fp32 -> xTc[t][b][v][c] bf16 (c contiguous)
__global__ void k_transpose_x(const float* __restrict__ x, unsigned short* __restrict__ xT){
  int tid = threadIdx.x;
  int c = tid & 63, vl = tid >> 6;
  int b = blockIdx.y;
  int v = blockIdx.x * 4 + vl;
  const float* xp = x + ((size_t)(b * Cn + c) * Vn + v) * Tn;
  float vals[24];
  #pragma unroll
  for (int q = 0; q < 6; ++q){
    float4 f = *(const float4*)(xp + q*4);
    vals[q*4+0]=f.x; vals[q*4+1]=f.y; vals[q*4+2]=f.z; vals[q*4+3]=f.w;
  }
  #pragma unroll
  for (int t = 0; t < Tn; ++t)
    xT[((size_t)(t*Bn + b) * Vn + v) * Cn + c] = f2bf(vals[t]);
}

// comb = x_t + h. Writes both layouts: combc[b][v][c] (gates B-op) and combmk[b*C+c][v] (GEMM A-op)
__global__ __launch_bounds__(256) void k_comb(const unsigned short* __restrict__ xTc,
    const unsigned short* __restrict__ ys,
    unsigned short* __restrict__ combc, unsigned short* __restrict__ combmk, int t){
  __shared__ float tile[64][65];
  int b = blockIdx.y, v0 = blockIdx.x * 64;
  const unsigned short* xp = xTc + ((size_t)t*Bn + b) * Vn * Cn;
  const unsigned short* hp = ys  + ((size_t)t*Bn + b) * Vn * Cn;   // plane t = h_{t-1} (plane0 = 0)
  for (int e = threadIdx.x; e < 4096; e += 256){
    int vl = e >> 6, c = e & 63;
    size_t o = (size_t)(v0 + vl) * Cn + c;
    float s = bf2f(xp[o]) + bf2f(hp[o]);
    combc[(size_t)b*Vn*Cn + o] = f2bf(s);
    tile[vl][c] = s;
  }
  __syncthreads();
  for (int e = threadIdx.x; e < 4096; e += 256){
    int c = e >> 6, vl = e & 63;
    combmk[((size_t)b*Cn + c)*Vn + v0 + vl] = f2bf(tile[vl][c]);
  }
}

// Dual GEMM: x1 = comb@A, x2 = comb@A2.  M=2048 (b*C+c), N=1024 (w), K=1024 (v).
// Outputs written transposed per batch: x?c[b][w][c] bf16 (c contiguous, for gates B-op).
__global__ __launch_bounds__(64) void k_dual(const unsigned short* __restrict__ comb_mk,
    const unsigned short* __restrict__ ATb, const unsigned short* __restrict__ A2Tb,
    unsigned short* __restrict__ x1c, unsigned short* __restrict__ x2c){
  int lane = threadIdx.x;
  int n0 = blockIdx.x * 64, m0 = blockIdx.y * 64;
  f32x4 acc1[4][4], acc2[4][4];
  #pragma unroll
  for (int i=0;i<4;i++)
    #pragma unroll
    for (int j=0;j<4;j++){ acc1[i][j] = fzero(); acc2[i][j] = fzero(); }
  #pragma unroll 2
  for (int k = 0; k < Vn; k += 32){
    bh8 a[4], b1[4], b2[4];
    #pragma unroll
    for (int mf=0; mf<4; ++mf) a[mf]  = ld_frag(comb_mk, Vn, m0, mf, k, lane);
    #pragma unroll
    for (int nf=0; nf<4; ++nf) b1[nf] = ld_frag(ATb,  Vn, n0, nf, k, lane);
    #pragma unroll
    for (int nf=0; nf<4; ++nf) b2[nf] = ld_frag(A2Tb, Vn, n0, nf, k, lane);
    #pragma unroll
    for (int mf=0; mf<4; ++mf)
      #pragma unroll
      for (int nf=0; nf<4; ++nf){
        acc1[mf][nf] = __builtin_amdgcn_mfma_f32_16x16x32_bf16(a[mf], b1[nf], acc1[mf][nf], 0,0,0);
        acc2[mf][nf] = __builtin_amdgcn_mfma_f32_16x16x32_bf16(a[mf], b2[nf], acc2[mf][nf], 0,0,0);
      }
  }
  int b = blockIdx.y;   // BM=64=C so m-tile == batch
  #pragma unroll
  for (int mf=0; mf<4; ++mf){
    int cb = mf*16 + ((lane>>4)<<2);   // first of 4 consecutive channels held by this lane
    #pragma unroll
    for (int nf=0; nf<4; ++nf){
      int w = n0 + nf*16 + (lane&15);
      bh4 p1, p2;
      #pragma unroll
      for (int r=0;r<4;r++){ p1[r] = (short)f2bf(acc1[mf][nf][r]); p2[r] = (short)f2bf(acc2[mf][nf][r]); }
      *(bh4*)(x1c + ((size_t)b*Vn + w)*Cn + cb) = p1;
      *(bh4*)(x2c + ((size_t)b*Vn + w)*Cn + cb) = p2;
    }
  }
}

// Gates GEMM (Wperm @ [comb;x1;x2]) + fused LSTM pointwise.
// M=256 (o'=c*4+gate), N=64 v-tile, K=192. Each lane's acc f32x4 = (i,f,cell,o) of one (c,v).
__global__ __launch_bounds__(64) void k_gates(const unsigned short* __restrict__ Wperm,
    const float* __restrict__ bperm,
    const unsigned short* __restrict__ combc, const unsigned short* __restrict__ x1c,
    const unsigned short* __restrict__ x2c,
    float* __restrict__ cst, unsigned short* __restrict__ ys, int t){
  int lane = threadIdx.x;
  int v0 = blockIdx.x * 64, m0 = blockIdx.y * 64, b = blockIdx.z;
  f32x4 acc[4][4];
  #pragma unroll
  for (int i=0;i<4;i++)
    #pragma unroll
    for (int j=0;j<4;j++) acc[i][j] = fzero();
  #pragma unroll
  for (int ki = 0; ki < 6; ++ki){
    int hop = ki >> 1, koff = (ki & 1) * 32;
    const unsigned short* hb = (hop == 0 ? combc : hop == 1 ? x1c : x2c) + (size_t)b * Vn * Cn;
    bh8 a[4], bb[4];
    #pragma unroll
    for (int mf=0; mf<4; ++mf) a[mf]  = ld_frag(Wperm, Gn, m0, mf, hop*64 + koff, lane);
    #pragma unroll
    for (int nf=0; nf<4; ++nf) bb[nf] = ld_frag(hb, Cn, v0, nf, koff, lane);
    #pragma unroll
    for (int mf=0; mf<4; ++mf)
      #pragma unroll
      for (int nf=0; nf<4; ++nf)
        acc[mf][nf] = __builtin_amdgcn_mfma_f32_16x16x32_bf16(a[mf], bb[nf], acc[mf][nf], 0,0,0);
  }
  unsigned short* ysp = ys + ((size_t)(t+1)*Bn + b) * Vn * Cn;  // plane t+1 = h_t
  #pragma unroll
  for (int mf = 0; mf < 4; ++mf){
    int oprow = m0 + mf*16 + ((lane>>4)<<2);
    int c = oprow >> 2;
    float bi  = bperm[oprow+0];
    float bff = bperm[oprow+1];
    float bgg = bperm[oprow+2];
    float boo = bperm[oprow+3];
    #pragma unroll
    for (int nf = 0; nf < 4; ++nf){
      int v = v0 + nf*16 + (lane & 15);
      float gi = sigm(acc[mf][nf][0] + bi);
      float gf = sigm(acc[mf][nf][1] + bff);
      float gg =      acc[mf][nf][2] + bgg;      // cell gate used raw (no tanh) per reference
      float go = sigm(acc[mf][nf][3] + boo);
      size_t ci = ((size_t)b*Cn + c)*Vn + v;
      float cy = gf * cst[ci] + gi * gg;
      cst[ci] = cy;
      ysp[(size_t)v*Cn + c] = f2bf(go * tanhfast(cy));
    }
  }
}

// Output projection + transpose: out[b][o][v][t] = sum_c Wout[o][c]*hy_t[b][c][v] + bout[o]
// Block: (t-chunk of 4, v-tile of 32, b). float4 stores along t (full 16B, no partial lines).
__global__ __launch_bounds__(256) void k_proj(const unsigned short* __restrict__ ys,
    const float* __restrict__ Wout, const float* __restrict__ bout, float* __restrict__ out){
  __shared__ float hyt[4][32][68];
  __shared__ float wt[64][68];
  int tc = blockIdx.x;          // 0..5
  int v0 = blockIdx.y * 32;
  int b  = blockIdx.z;
  int tid = threadIdx.x;
  for (int e = tid; e < 4096; e += 256){ int o = e>>6, c = e&63; wt[o][c] = Wout[(size_t)o*64 + c]; }
  for (int e = tid; e < 8192; e += 256){
    int tt = e >> 11; int rem = e & 2047; int vl = rem >> 6; int c = rem & 63;
    int plane = tc*4 + tt + 1;
    hyt[tt][vl][c] = bf2f(ys[((size_t)plane*Bn + b)*Vn*Cn + (size_t)(v0+vl)*Cn + c]);
  }
  __syncthreads();
  int og = tid >> 3, vg = tid & 7;   // 32 o-groups x 8 v-groups; 2 o's, 4 v's each
  float acc[2][4][4];
  #pragma unroll
  for (int i=0;i<2;i++)
    #pragma unroll
    for (int j=0;j<4;j++)
      #pragma unroll
      for (int k=0;k<4;k++) acc[i][j][k] = 0.f;
  for (int c = 0; c < 64; c += 4){
    float4 w4[2];
    #pragma unroll
    for (int oo=0;oo<2;oo++) w4[oo] = *(const float4*)&wt[og*2+oo][c];
    #pragma unroll
    for (int vv=0; vv<4; ++vv)
      #pragma unroll
      for (int tt=0; tt<4; ++tt){
        float4 h4 = *(const float4*)&hyt[tt][vg*4+vv][c];
        #pragma unroll
        for (int oo=0;oo<2;oo++)
          acc[oo][vv][tt] += w4[oo].x*h4.x + w4[oo].y*h4.y + w4[oo].z*h4.z + w4[oo].w*h4.w;
      }
  }
  #pragma unroll
  for (int oo=0;oo<2;oo++){
    int o = og*2 + oo;
    float bo = bout[o];
    #pragma unroll
    for (int vv=0; vv<4; ++vv){
      int v = v0 + vg*4 + vv;
      float4 r4;
      r4.x = acc[oo][vv][0] + bo; r4.y = acc[oo][vv][1] + bo;
      r4.z = acc[oo][vv][2] + bo; r4.w = acc[oo][vv][3] + bo;
      *(float4*)(out + ((size_t)(b*64 + o)*Vn + v)*Tn + tc*4) = r4;
    }
  }
}

// ---------------------------------------------------------------------------
extern "C" void kernel_launch(void* const* d_in, const int* in_sizes, int n_in,
                              void* d_out, int out_size, void* d_ws, size_t ws_size,
                              hipStream_t stream){
  const float* x   = (const float*)d_in[0];
  const float* A   = (const float*)d_in[1];
  const float* Wg  = (const float*)d_in[2];
  const float* bg  = (const float*)d_in[3];
  const float* Wo  = (const float*)d_in[4];
  const float* bo  = (const float*)d_in[5];
  float* out = (float*)d_out;

  char* ws = (char*)d_ws;
  size_t off = 0;
  auto alloc = [&](size_t bytes)->char*{
    char* p = ws + off; off = (off + bytes + 255) & ~(size_t)255; return p;
  };
  unsigned short* Abf    = (unsigned short*)alloc((size_t)Vn*Vn*2);
  unsigned short* ATbf   = (unsigned short*)alloc((size_t)Vn*Vn*2);
  unsigned short* A2T    = (unsigned short*)alloc((size_t)Vn*Vn*2);
  float*          A2f    = (float*)         alloc((size_t)Vn*Vn*4);
  unsigned short* Wperm  = (unsigned short*)alloc((size_t)O4*Gn*2);
  float*          bperm  = (float*)         alloc((size_t)O4*4);
  unsigned short* xTc    = (unsigned short*)alloc((size_t)Tn*Bn*Vn*Cn*2);
  unsigned short* ys     = (unsigned short*)alloc((size_t)(Tn+1)*Bn*Vn*Cn*2);
  unsigned short* combc  = (unsigned short*)alloc((size_t)Bn*Vn*Cn*2);
  unsigned short* combmk = (unsigned short*)alloc((size_t)Bn*Cn*Vn*2);
  unsigned short* x1c    = (unsigned short*)alloc((size_t)Bn*Vn*Cn*2);
  unsigned short* x2c    = (unsigned short*)alloc((size_t)Bn*Vn*Cn*2);
  float*          cst    = (float*)         alloc((size_t)Bn*Cn*Vn*4);
  (void)in_sizes; (void)n_in; (void)out_size; (void)ws_size;

  // zero-init recurrent state (h0 plane of ys, c0)
  hipMemsetAsync(ys,  0, (size_t)Bn*Vn*Cn*2, stream);
  hipMemsetAsync(cst, 0, (size_t)Bn*Cn*Vn*4, stream);

  k_prep_w<<<1, 256, 0, stream>>>(Wg, bg, Wperm, bperm);
  k_transq<<<dim3(16,16), 256, 0, stream>>>(A, Abf, ATbf);
  k_gemm_a2<<<dim3(16,16), 64, 0, stream>>>(Abf, ATbf, A2f);
  k_transq<<<dim3(16,16), 256, 0, stream>>>(A2f, (unsigned short*)nullptr, A2T);
  k_transpose_x<<<dim3(256,32), 256, 0, stream>>>(x, xTc);

  for (int t = 0; t < Tn; ++t){
    k_comb <<<dim3(16,Bn),    256, 0, stream>>>(xTc, ys, combc, combmk, t);
    k_dual <<<dim3(16,32),     64, 0, stream>>>(combmk, ATbf, A2T, x1c, x2c);
    k_gates<<<dim3(16,4,Bn),   64, 0, stream>>>(Wperm, bperm, combc, x1c, x2c, cst, ys, t);
  }
  k_proj<<<dim3(6,32,Bn), 256, 0, stream>>>(ys, Wo, bo, out);
}